// Round 8
// baseline (4179.949 us; speedup 1.0000x reference)
//
#include <hip/hip_runtime.h>
#include <hip/hip_fp16.h>
#include <math.h>

#define NN 50000
#define NE 1600000
#define CC 128
#define FIN 64

typedef unsigned short bfr;
typedef __attribute__((ext_vector_type(8))) short short8;
typedef __attribute__((ext_vector_type(4))) float f32x4;

__device__ __forceinline__ f32x4 mfma16(short8 a, short8 b, f32x4 c) {
  return __builtin_amdgcn_mfma_f32_16x16x32_bf16(a, b, c, 0, 0, 0);
}

__device__ __forceinline__ float silu_f(float x) { return x / (1.0f + __expf(-x)); }
__device__ __forceinline__ float gelu_f(float x) { return 0.5f * x * (1.0f + erff(x * 0.7071067811865475f)); }

__device__ __forceinline__ bfr f2bf(float x) {
  unsigned u = __float_as_uint(x);
  unsigned r = (u + 0x7FFFu + ((u >> 16) & 1u)) >> 16;
  return (bfr)r;
}
__device__ __forceinline__ float bf2f(bfr h) { return __uint_as_float(((unsigned)h) << 16); }

// pack the high 16 bits of two fp32 into one u32 (a -> low16, b -> high16)
__device__ __forceinline__ unsigned pack_hi16(unsigned ua, unsigned ub) {
  return __builtin_amdgcn_perm(ub, ua, 0x07060302u);
}

__device__ __forceinline__ float hsum32(float v) {
  v += __shfl_xor(v, 16);
  v += __shfl_xor(v, 8);
  v += __shfl_xor(v, 4);
  v += __shfl_xor(v, 2);
  v += __shfl_xor(v, 1);
  return v;
}

// ============================ dst-sort (counting sort via CSR) ==================================
__global__ __launch_bounds__(256)
void hist_kernel(const int* __restrict__ dst, int* __restrict__ cnt)
{
  const int i = blockIdx.x * 256 + threadIdx.x;
  if (i < NE) atomicAdd(&cnt[dst[i]], 1);
}

__global__ __launch_bounds__(1024)
void scan_kernel(const int* __restrict__ cnt, int* __restrict__ next)
{
  __shared__ int part[1024];
  const int tid = threadIdx.x;
  const int per = (NN + 1023) / 1024;   // 49
  const int base = tid * per;
  int s = 0;
  for (int i = 0; i < per; ++i) {
    const int n = base + i;
    if (n < NN) s += cnt[n];
  }
  part[tid] = s;
  __syncthreads();
  if (tid == 0) {
    int acc = 0;
    for (int i = 0; i < 1024; ++i) { const int t = part[i]; part[i] = acc; acc += t; }
  }
  __syncthreads();
  int off = part[tid];
  for (int i = 0; i < per; ++i) {
    const int n = base + i;
    if (n < NN) { next[n] = off; off += cnt[n]; }
  }
}

__global__ __launch_bounds__(256)
void slot_kernel(const int* __restrict__ dst, int* __restrict__ next, int* __restrict__ perm)
{
  const int i = blockIdx.x * 256 + threadIdx.x;
  if (i < NE) perm[atomicAdd(&next[dst[i]], 1)] = i;
}

// ============================ weight split: Wt_hi/lo[l][n][k] = split(W[l][k][n]) ===============
__global__ __launch_bounds__(256)
void wt_split(const float* __restrict__ W, bfr* __restrict__ Wh, bfr* __restrict__ Wl,
              const int K, const int layers, const int strideIn)
{
  const int gid = blockIdx.x * 256 + threadIdx.x;
  if (gid >= layers * 128 * K) return;
  const int l = gid / (128 * K);
  const int rem = gid - l * 128 * K;
  const int n = rem / K;
  const int k = rem - n * K;
  const float w = W[(size_t)l * strideIn + (size_t)k * 128 + n];
  const bfr hi = f2bf(w);
  Wh[gid] = hi;
  Wl[gid] = f2bf(w - bf2f(hi));
}

// ============================ PQ precompute: P|Q = h @ [W1a|W1b] (+eb1 on P), fp16 out ==========
__global__ __launch_bounds__(256)
void pq_kernel(const bfr* __restrict__ h_hi, const bfr* __restrict__ h_lo,
               const bfr* __restrict__ W1h, const bfr* __restrict__ W1l,
               const float* __restrict__ eb1, __half* __restrict__ PQ)
{
  __shared__ __align__(16) bfr ah[2 * 32 * 136];   // A hi|lo, stride 136 (17,408 B)
  const int tid = threadIdx.x;
  const int n0 = blockIdx.x * 32;
  {
    const int row = tid >> 3, q = tid & 7;
    int n = n0 + row; if (n >= NN) n = NN - 1;
    const uint4* sh = (const uint4*)(h_hi + (size_t)n * CC) + q * 2;
    const uint4* sl = (const uint4*)(h_lo + (size_t)n * CC) + q * 2;
    uint4* dh = (uint4*)(ah + row * 136) + q * 2;
    uint4* dl = (uint4*)(ah + 32 * 136 + row * 136) + q * 2;
    dh[0] = sh[0]; dh[1] = sh[1];
    dl[0] = sl[0]; dl[1] = sl[1];
  }
  __syncthreads();

  const int lane = tid & 63;
  const int li = lane & 15, quad = lane >> 4;
  const int wv = tid >> 6;
  const int c0 = wv * 32 + li, c1 = c0 + 16;

  f32x4 acc[2][4];  // [mi][Pc0, Pc1, Qc0, Qc1]
  {
    const float b0 = eb1[c0], b1 = eb1[c1];
    acc[0][0] = acc[1][0] = (f32x4){b0, b0, b0, b0};
    acc[0][1] = acc[1][1] = (f32x4){b1, b1, b1, b1};
    acc[0][2] = acc[1][2] = (f32x4){0, 0, 0, 0};
    acc[0][3] = acc[1][3] = (f32x4){0, 0, 0, 0};
  }
  const bfr* bp[4] = { W1h + (size_t)c0 * 256, W1h + (size_t)c1 * 256,
                       W1h + (size_t)c0 * 256 + 128, W1h + (size_t)c1 * 256 + 128 };
  const bfr* lp[4] = { W1l + (size_t)c0 * 256, W1l + (size_t)c1 * 256,
                       W1l + (size_t)c0 * 256 + 128, W1l + (size_t)c1 * 256 + 128 };
  #pragma unroll
  for (int ks = 0; ks < 4; ++ks) {
    const int ko = ks * 32 + quad * 8;
    short8 Bh[4], Bl[4];
    #pragma unroll
    for (int o = 0; o < 4; ++o) { Bh[o] = *(const short8*)(bp[o] + ko); Bl[o] = *(const short8*)(lp[o] + ko); }
    #pragma unroll
    for (int mi = 0; mi < 2; ++mi) {
      const int ao = (mi * 16 + li) * 136 + ko;
      const short8 Ah = *(const short8*)(ah + ao);
      const short8 Al = *(const short8*)(ah + 32 * 136 + ao);
      #pragma unroll
      for (int o = 0; o < 4; ++o) {
        acc[mi][o] = mfma16(Ah, Bh[o], acc[mi][o]);
        acc[mi][o] = mfma16(Al, Bh[o], acc[mi][o]);
        acc[mi][o] = mfma16(Ah, Bl[o], acc[mi][o]);
      }
    }
  }
  const int cmap[4] = { c0, c1, 128 + c0, 128 + c1 };
  #pragma unroll
  for (int mi = 0; mi < 2; ++mi) {
    #pragma unroll
    for (int r = 0; r < 4; ++r) {
      const int n = n0 + mi * 16 + quad * 4 + r;
      if (n < NN) {
        __half* po = PQ + (size_t)n * 256;
        #pragma unroll
        for (int o = 0; o < 4; ++o) po[cmap[o]] = __float2half(acc[mi][o][r]);
      }
    }
  }
}

// ============================ edge kernel (dst-sorted; register A-frags, no m1 LDS) =============
// Block b: sorted edges [b*64, b*64+64), dst nondecreasing. Wave wv owns C rows wv*16..+16 and
// ALL 128 output columns. Lane (li,quad) computes m1 for edge wv*16+li, channels ks*32+quad*8..+8
// == its GEMM2 A-fragment (registers, trunc hi/lo). B frags (full W2 hi/lo per wave) stream from
// L1/L2. C rows land at wv*16+quad*4+r, col n*16+li -> same scan shape as R7.
template<int COORD>
__global__ __launch_bounds__(256)
void edge_kernel(const int* __restrict__ perm,
                 const int* __restrict__ src, const int* __restrict__ dst,
                 const __half* __restrict__ PQ, const float* __restrict__ xyz,
                 const float* __restrict__ w1rad,
                 const bfr* __restrict__ W2h, const bfr* __restrict__ W2l,
                 const float* __restrict__ eb2,
                 const bfr* __restrict__ W3h, const bfr* __restrict__ W3l,
                 const float* __restrict__ cb1, const float* __restrict__ cw2,
                 float* __restrict__ h_agg, float* __restrict__ x_agg)
{
  const int EPB = 64;
  constexpr int SBYTES = COORD ? (2 * 64 * 136 * 2) : (64 * 132 * 4);  // 34,816 / 33,792
  __shared__ __align__(16) unsigned char smem[SBYTES];
  __shared__ int sidx[EPB], didx[EPB];
  __shared__ float radial[EPB];
  __shared__ float xdn[COORD ? EPB : 1][3];
  __shared__ float sx[COORD ? EPB : 1];
  __shared__ float cw2s[COORD ? 128 : 1];

  const int tid = threadIdx.x;
  const size_t ebase = (size_t)blockIdx.x * EPB;

  if (tid < EPB) {
    const int e = perm[ebase + tid];
    const int s = src[e], d = dst[e];
    sidx[tid] = s; didx[tid] = d;
    const float* xs = xyz + (size_t)s * 3;
    const float* xd = xyz + (size_t)d * 3;
    const float dx = xs[0] - xd[0], dy = xs[1] - xd[1], dz = xs[2] - xd[2];
    const float r = dx * dx + dy * dy + dz * dz;
    radial[tid] = r;
    if (COORD) {
      const float inv = 1.0f / (sqrtf(r) + 1e-30f);
      xdn[tid][0] = dx * inv; xdn[tid][1] = dy * inv; xdn[tid][2] = dz * inv;
    }
  }
  if (COORD && tid >= 128) cw2s[tid - 128] = cw2[tid - 128];
  __syncthreads();

  const int lane = tid & 63, wv = tid >> 6;
  const int li = lane & 15, quad = lane >> 4;
  const int row = wv * 16 + li;      // the edge whose A-fragment this lane owns

  // ---- m1 = silu(P[src]+Q[dst]+r*w1rad) straight into register A-fragments (trunc hi/lo) -----
  short8 Ah[4], Al[4];
  {
    const int s = sidx[row], d = didx[row];
    const float r = radial[row];
    const __half* prow = PQ + (size_t)s * 256;
    const __half* qrow = PQ + (size_t)d * 256 + 128;
    #pragma unroll
    for (int ks = 0; ks < 4; ++ks) {
      const int ch = ks * 32 + quad * 8;
      union { uint4 u; __half2 h2[4]; } pu, qu;
      pu.u = *(const uint4*)(prow + ch);
      qu.u = *(const uint4*)(qrow + ch);
      const float4 wa = *(const float4*)(w1rad + ch);
      const float4 wb = *(const float4*)(w1rad + ch + 4);
      const float wf[8] = { wa.x, wa.y, wa.z, wa.w, wb.x, wb.y, wb.z, wb.w };
      float v[8];
      #pragma unroll
      for (int j = 0; j < 4; ++j) {
        const float2 p = __half22float2(pu.h2[j]);
        const float2 q = __half22float2(qu.h2[j]);
        v[2 * j]     = silu_f(p.x + q.x + r * wf[2 * j]);
        v[2 * j + 1] = silu_f(p.y + q.y + r * wf[2 * j + 1]);
      }
      union { uint4 u; short8 s8; } H, L;
      unsigned hw[4], lw[4];
      #pragma unroll
      for (int j = 0; j < 4; ++j) {
        const unsigned ua = __float_as_uint(v[2 * j]);
        const unsigned ub = __float_as_uint(v[2 * j + 1]);
        const float la = v[2 * j]     - __uint_as_float(ua & 0xFFFF0000u);
        const float lb = v[2 * j + 1] - __uint_as_float(ub & 0xFFFF0000u);
        hw[j] = pack_hi16(ua, ub);
        lw[j] = pack_hi16(__float_as_uint(la), __float_as_uint(lb));
      }
      H.u = make_uint4(hw[0], hw[1], hw[2], hw[3]);
      L.u = make_uint4(lw[0], lw[1], lw[2], lw[3]);
      Ah[ks] = H.s8; Al[ks] = L.s8;
    }
  }

  // ---- GEMM2: bf16x3, A from registers, B = full W2 per wave ---------------------------------
  f32x4 acc[8];
  #pragma unroll
  for (int n = 0; n < 8; ++n) {
    const float b = eb2[n * 16 + li];
    acc[n] = (f32x4){b, b, b, b};
  }
  #pragma unroll
  for (int n = 0; n < 8; ++n) {
    const bfr* bh = W2h + (size_t)(n * 16 + li) * 128 + quad * 8;
    const bfr* bl = W2l + (size_t)(n * 16 + li) * 128 + quad * 8;
    #pragma unroll
    for (int ks = 0; ks < 4; ++ks) {
      const short8 Bh = *(const short8*)(bh + ks * 32);
      const short8 Bl = *(const short8*)(bl + ks * 32);
      acc[n] = mfma16(Ah[ks], Bh, acc[n]);
      acc[n] = mfma16(Al[ks], Bh, acc[n]);
      acc[n] = mfma16(Ah[ks], Bl, acc[n]);
    }
  }
  #pragma unroll
  for (int n = 0; n < 8; ++n) {
    #pragma unroll
    for (int r = 0; r < 4; ++r) acc[n][r] = silu_f(acc[n][r]);
  }

  const int crow0 = wv * 16 + quad * 4;

  if (!COORD) {
    // ---- m fp32 -> tbuf (stride 132) -> per-channel 32-row segmented scan --------------------
    float* tbuf = (float*)smem;
    #pragma unroll
    for (int n = 0; n < 8; ++n) {
      #pragma unroll
      for (int r = 0; r < 4; ++r)
        tbuf[(crow0 + r) * 132 + n * 16 + li] = acc[n][r];
    }
    __syncthreads();
    const int c = tid & 127, half = tid >> 7;
    const int j0 = half * 32, j1 = j0 + 32;
    float s = 0.0f;
    for (int j = j0; j < j1; ++j) {
      s += tbuf[j * 132 + c];
      const int dj = didx[j];
      if (j == j1 - 1 || didx[j + 1] != dj) {
        atomicAdd(&h_agg[(size_t)dj * CC + c], s);
        s = 0.0f;
      }
    }
  } else {
    // ---- m hi/lo (trunc) -> mb (A of GEMM3) --------------------------------------------------
    bfr* mb = (bfr*)smem;
    const int MOFF = 64 * 136;
    #pragma unroll
    for (int n = 0; n < 8; ++n) {
      #pragma unroll
      for (int r = 0; r < 4; ++r) {
        const int rw = crow0 + r, cl = n * 16 + li;
        const float v = acc[n][r];
        const unsigned u = __float_as_uint(v);
        mb[rw * 136 + cl] = (bfr)(u >> 16);
        const float l = v - __uint_as_float(u & 0xFFFF0000u);
        mb[MOFF + rw * 136 + cl] = (bfr)(__float_as_uint(l) >> 16);
      }
    }
    __syncthreads();
    // ---- segmented scan over hi+lo -----------------------------------------------------------
    {
      const int c = tid & 127, half = tid >> 7;
      const int j0 = half * 32, j1 = j0 + 32;
      float s = 0.0f;
      for (int j = j0; j < j1; ++j) {
        s += bf2f(mb[j * 136 + c]) + bf2f(mb[MOFF + j * 136 + c]);
        const int dj = didx[j];
        if (j == j1 - 1 || didx[j + 1] != dj) {
          atomicAdd(&h_agg[(size_t)dj * CC + c], s);
          s = 0.0f;
        }
      }
    }
    // ---- GEMM3: A = m from mb, B = full W3 per wave ------------------------------------------
    f32x4 tt[8];
    #pragma unroll
    for (int n = 0; n < 8; ++n) {
      const float b = cb1[n * 16 + li];
      tt[n] = (f32x4){b, b, b, b};
    }
    {
      short8 Ah3[4], Al3[4];
      #pragma unroll
      for (int ks = 0; ks < 4; ++ks) {
        const int ao = row * 136 + ks * 32 + quad * 8;
        Ah3[ks] = *(const short8*)(mb + ao);
        Al3[ks] = *(const short8*)(mb + MOFF + ao);
      }
      #pragma unroll
      for (int n = 0; n < 8; ++n) {
        const bfr* bh = W3h + (size_t)(n * 16 + li) * 128 + quad * 8;
        const bfr* bl = W3l + (size_t)(n * 16 + li) * 128 + quad * 8;
        #pragma unroll
        for (int ks = 0; ks < 4; ++ks) {
          const short8 Bh = *(const short8*)(bh + ks * 32);
          const short8 Bl = *(const short8*)(bl + ks * 32);
          tt[n] = mfma16(Ah3[ks], Bh, tt[n]);
          tt[n] = mfma16(Al3[ks], Bh, tt[n]);
          tt[n] = mfma16(Ah3[ks], Bl, tt[n]);
        }
      }
    }
    __syncthreads();   // scan + GEMM3 reads of mb done before alias
    float* tbuf = (float*)smem;  // 64 x 132 fp32 = 33,792 B <= 34,816 B
    #pragma unroll
    for (int n = 0; n < 8; ++n) {
      #pragma unroll
      for (int r = 0; r < 4; ++r)
        tbuf[(crow0 + r) * 132 + n * 16 + li] = silu_f(tt[n][r]);
    }
    __syncthreads();
    if (tid < EPB) {
      float s = 0.0f;
      #pragma unroll 8
      for (int k = 0; k < CC; ++k) s += tbuf[tid * 132 + k] * cw2s[k];
      sx[tid] = s;
    }
    __syncthreads();
    if (tid < 6) {
      const int c = tid >> 1, half = tid & 1;
      const int j0 = half * 32, j1 = j0 + 32;
      float a = 0.0f;
      for (int j = j0; j < j1; ++j) {
        a += sx[j] * xdn[j][c];
        const int dj = didx[j];
        if (j == j1 - 1 || didx[j + 1] != dj) {
          atomicAdd(&x_agg[(size_t)dj * 3 + c], a);
          a = 0.0f;
        }
      }
    }
  }
}

// ============================ fp32 node-side kernels (validated R3/R5) ==========================
template<int K, int ROWS>
__device__ __forceinline__ void mm_tile(const float* __restrict__ fb, const int fstride,
                                        const float* __restrict__ W, const float* __restrict__ bias,
                                        const int c0, const int r0, float (&acc)[ROWS][4])
{
  const float4 b = *(const float4*)(bias + c0);
  #pragma unroll
  for (int i = 0; i < ROWS; ++i) { acc[i][0] = b.x; acc[i][1] = b.y; acc[i][2] = b.z; acc[i][3] = b.w; }
  #pragma unroll 2
  for (int k = 0; k < K; k += 4) {
    const float4 w0 = *(const float4*)(W + (size_t)(k + 0) * CC + c0);
    const float4 w1 = *(const float4*)(W + (size_t)(k + 1) * CC + c0);
    const float4 w2 = *(const float4*)(W + (size_t)(k + 2) * CC + c0);
    const float4 w3 = *(const float4*)(W + (size_t)(k + 3) * CC + c0);
    #pragma unroll
    for (int i = 0; i < ROWS; ++i) {
      const float4 f = *(const float4*)(fb + (r0 + i) * fstride + k);
      acc[i][0] += f.x * w0.x + f.y * w1.x + f.z * w2.x + f.w * w3.x;
      acc[i][1] += f.x * w0.y + f.y * w1.y + f.z * w2.y + f.w * w3.y;
      acc[i][2] += f.x * w0.z + f.y * w1.z + f.z * w2.z + f.w * w3.z;
      acc[i][3] += f.x * w0.w + f.y * w1.w + f.z * w2.w + f.w * w3.w;
    }
  }
}

__device__ __forceinline__ void ln_then_gelu(float (&v)[4], const float* __restrict__ g,
                                             const float* __restrict__ b, const int c0)
{
  const float mu = hsum32(v[0] + v[1] + v[2] + v[3]) * (1.0f / 128.0f);
  const float d0 = v[0] - mu, d1 = v[1] - mu, d2 = v[2] - mu, d3 = v[3] - mu;
  const float var = hsum32(d0 * d0 + d1 * d1 + d2 * d2 + d3 * d3) * (1.0f / 128.0f);
  const float rs = rsqrtf(var + 1e-5f);
  const float4 gv = *(const float4*)(g + c0);
  const float4 bv = *(const float4*)(b + c0);
  v[0] = gelu_f(d0 * rs * gv.x + bv.x);
  v[1] = gelu_f(d1 * rs * gv.y + bv.y);
  v[2] = gelu_f(d2 * rs * gv.z + bv.z);
  v[3] = gelu_f(d3 * rs * gv.w + bv.w);
}

__device__ __forceinline__ void store_hilo4(bfr* __restrict__ hi, bfr* __restrict__ lo,
                                            const float v0, const float v1,
                                            const float v2, const float v3)
{
  ushort4 h, l;
  h.x = f2bf(v0); h.y = f2bf(v1); h.z = f2bf(v2); h.w = f2bf(v3);
  l.x = f2bf(v0 - bf2f(h.x)); l.y = f2bf(v1 - bf2f(h.y));
  l.z = f2bf(v2 - bf2f(h.z)); l.w = f2bf(v3 - bf2f(h.w));
  *(ushort4*)hi = h;
  *(ushort4*)lo = l;
}

__global__ __launch_bounds__(256)
void node_update(const bfr* __restrict__ h_hi, const bfr* __restrict__ h_lo,
                 const float* __restrict__ h_agg,
                 const float* __restrict__ nw1, const float* __restrict__ nb1,
                 const float* __restrict__ nw2, const float* __restrict__ nb2,
                 bfr* __restrict__ ho_hi, bfr* __restrict__ ho_lo, const int post_ln,
                 const float* __restrict__ lng, const float* __restrict__ lnb,
                 const int do_coord, const float* __restrict__ xin,
                 const float* __restrict__ x_agg, float* __restrict__ coord_out)
{
  const int FS2 = 260, MS = 132;
  __shared__ float fin[16 * FS2];
  __shared__ float hid[16 * MS];
  const int tid = threadIdx.x;
  const size_t n0 = (size_t)blockIdx.x * 16;
  {
    const int n = tid >> 4, q = tid & 15;
    const uint4 vh = *(const uint4*)(h_hi + (n0 + n) * CC + q * 8);
    const uint4 vl = *(const uint4*)(h_lo + (n0 + n) * CC + q * 8);
    const unsigned short* hp = (const unsigned short*)&vh;
    const unsigned short* lp = (const unsigned short*)&vl;
    float* fo = fin + n * FS2 + q * 8;
    #pragma unroll
    for (int i = 0; i < 8; ++i) fo[i] = bf2f(hp[i]) + bf2f(lp[i]);
    const float4* s2 = (const float4*)(h_agg + (n0 + n) * CC + q * 8);
    float4* d2 = (float4*)(fin + n * FS2 + CC + q * 8);
    d2[0] = s2[0]; d2[1] = s2[1];
  }
  if (do_coord && tid < 48) {
    const int n = tid / 3, d = tid % 3;
    coord_out[(n0 + n) * 3 + d] = xin[(n0 + n) * 3 + d] + x_agg[(n0 + n) * 3 + d];
  }
  __syncthreads();
  const int cg = tid & 31, ng = tid >> 5;
  const int c0 = cg * 4, m0 = ng * 2;
  float acc[2][4];
  mm_tile<256, 2>(fin, FS2, nw1, nb1, c0, m0, acc);
  #pragma unroll
  for (int i = 0; i < 2; ++i) {
    float4 o;
    o.x = silu_f(acc[i][0]); o.y = silu_f(acc[i][1]); o.z = silu_f(acc[i][2]); o.w = silu_f(acc[i][3]);
    *(float4*)(hid + (m0 + i) * MS + c0) = o;
  }
  __syncthreads();
  float acc2[2][4];
  mm_tile<128, 2>(hid, MS, nw2, nb2, c0, m0, acc2);
  if (post_ln) {
    #pragma unroll
    for (int i = 0; i < 2; ++i) {
      float v[4] = { gelu_f(acc2[i][0]), gelu_f(acc2[i][1]), gelu_f(acc2[i][2]), gelu_f(acc2[i][3]) };
      const float mu = hsum32(v[0] + v[1] + v[2] + v[3]) * (1.0f / 128.0f);
      const float d0 = v[0] - mu, d1 = v[1] - mu, d2 = v[2] - mu, d3 = v[3] - mu;
      const float var = hsum32(d0 * d0 + d1 * d1 + d2 * d2 + d3 * d3) * (1.0f / 128.0f);
      const float rs = rsqrtf(var + 1e-5f);
      const float4 gv = *(const float4*)(lng + c0);
      const float4 bv = *(const float4*)(lnb + c0);
      acc2[i][0] = d0 * rs * gv.x + bv.x; acc2[i][1] = d1 * rs * gv.y + bv.y;
      acc2[i][2] = d2 * rs * gv.z + bv.z; acc2[i][3] = d3 * rs * gv.w + bv.w;
    }
  }
  #pragma unroll
  for (int i = 0; i < 2; ++i)
    store_hilo4(ho_hi + (n0 + m0 + i) * CC + c0, ho_lo + (n0 + m0 + i) * CC + c0,
                acc2[i][0], acc2[i][1], acc2[i][2], acc2[i][3]);
}

__global__ __launch_bounds__(256)
void embed_kernel(const float* __restrict__ na,
                  const float* __restrict__ w1, const float* __restrict__ b1,
                  const float* __restrict__ g1, const float* __restrict__ be1,
                  const float* __restrict__ w2, const float* __restrict__ b2,
                  const float* __restrict__ g2, const float* __restrict__ be2,
                  bfr* __restrict__ ho_hi, bfr* __restrict__ ho_lo)
{
  const int AS = 68, MS = 132;
  __shared__ float ain[16 * AS];
  __shared__ float hb[16 * MS];
  const int tid = threadIdx.x;
  const size_t n0 = (size_t)blockIdx.x * 16;
  {
    const int n = tid >> 4, q = tid & 15;
    *(float4*)(ain + n * AS + q * 4) = *(const float4*)(na + (n0 + n) * FIN + q * 4);
  }
  __syncthreads();
  const int cg = tid & 31, ng = tid >> 5;
  const int c0 = cg * 4, m0 = ng * 2;
  float acc[2][4];
  mm_tile<64, 2>(ain, AS, w1, b1, c0, m0, acc);
  #pragma unroll
  for (int i = 0; i < 2; ++i) {
    ln_then_gelu(acc[i], g1, be1, c0);
    *(float4*)(hb + (m0 + i) * MS + c0) = make_float4(acc[i][0], acc[i][1], acc[i][2], acc[i][3]);
  }
  __syncthreads();
  float acc2[2][4];
  mm_tile<128, 2>(hb, MS, w2, b2, c0, m0, acc2);
  #pragma unroll
  for (int i = 0; i < 2; ++i) {
    ln_then_gelu(acc2[i], g2, be2, c0);
    store_hilo4(ho_hi + (n0 + m0 + i) * CC + c0, ho_lo + (n0 + m0 + i) * CC + c0,
                acc2[i][0], acc2[i][1], acc2[i][2], acc2[i][3]);
  }
}

__global__ __launch_bounds__(192)
void out_kernel(const bfr* __restrict__ h_hi, const bfr* __restrict__ h_lo,
                const float* __restrict__ w, const float* __restrict__ b,
                float* __restrict__ out)
{
  const int gid = blockIdx.x * 192 + threadIdx.x;
  if (gid >= NN * 3) return;
  const int n = gid / 3, j = gid % 3;
  float acc = b[j];
  const bfr* hh = h_hi + (size_t)n * CC;
  const bfr* hl = h_lo + (size_t)n * CC;
  #pragma unroll 4
  for (int k = 0; k < CC; ++k) acc += (bf2f(hh[k]) + bf2f(hl[k])) * w[k * 3 + j];
  out[gid] = acc;
}

// ================================================================================================
extern "C" void kernel_launch(void* const* d_in, const int* in_sizes, int n_in,
                              void* d_out, int out_size, void* d_ws, size_t ws_size,
                              hipStream_t stream)
{
  (void)in_sizes; (void)n_in; (void)out_size; (void)ws_size;
  const int*   src       = (const int*)d_in[0];
  const int*   dst       = (const int*)d_in[1];
  const float* node_attr = (const float*)d_in[2];
  const float* xyz       = (const float*)d_in[3];
  const float* emb_w1    = (const float*)d_in[4];
  const float* emb_b1    = (const float*)d_in[5];
  const float* ln1_g     = (const float*)d_in[6];
  const float* ln1_b     = (const float*)d_in[7];
  const float* emb_w2    = (const float*)d_in[8];
  const float* emb_b2    = (const float*)d_in[9];
  const float* ln2_g     = (const float*)d_in[10];
  const float* ln2_b     = (const float*)d_in[11];
  const float* e_w1      = (const float*)d_in[12];
  const float* e_b1      = (const float*)d_in[13];
  const float* e_w2      = (const float*)d_in[14];
  const float* e_b2      = (const float*)d_in[15];
  const float* n_w1      = (const float*)d_in[16];
  const float* n_b1      = (const float*)d_in[17];
  const float* n_w2      = (const float*)d_in[18];
  const float* n_b2      = (const float*)d_in[19];
  const float* c_w1      = (const float*)d_in[20];
  const float* c_b1      = (const float*)d_in[21];
  const float* c_w2      = (const float*)d_in[22];
  const float* dec_ln_g  = (const float*)d_in[23];
  const float* dec_ln_b  = (const float*)d_in[24];
  const float* out_w     = (const float*)d_in[25];
  const float* out_b     = (const float*)d_in[26];

  // workspace layout (~86 MB total)
  char* wsb = (char*)d_ws;
  float*  h_agg = (float*)wsb;                      wsb += (size_t)NN * CC * 4;   // 25.6 MB
  __half* PQ    = (__half*)wsb;                     wsb += (size_t)NN * 256 * 2;  // 25.6 MB
  float*  x_agg = (float*)wsb;                      wsb += (size_t)NN * 3 * 4;
  float*  coord = (float*)wsb;                      wsb += (size_t)NN * 3 * 4;
  bfr*    h_hi  = (bfr*)wsb;                        wsb += (size_t)NN * CC * 2;   // 12.8 MB
  bfr*    h_lo  = (bfr*)wsb;                        wsb += (size_t)NN * CC * 2;   // 12.8 MB
  bfr*    W1h   = (bfr*)wsb;                        wsb += (size_t)3 * 128 * 256 * 2;
  bfr*    W1l   = (bfr*)wsb;                        wsb += (size_t)3 * 128 * 256 * 2;
  bfr*    W2h   = (bfr*)wsb;                        wsb += (size_t)3 * 128 * 128 * 2;
  bfr*    W2l   = (bfr*)wsb;                        wsb += (size_t)3 * 128 * 128 * 2;
  bfr*    W3h   = (bfr*)wsb;                        wsb += (size_t)128 * 128 * 2;
  bfr*    W3l   = (bfr*)wsb;                        wsb += (size_t)128 * 128 * 2;
  int*    permA = (int*)wsb;                        wsb += (size_t)NE * 4;        // 6.4 MB
  int*    cnt   = (int*)wsb;                        wsb += (size_t)NN * 4;
  int*    nextA = (int*)wsb;                        wsb += (size_t)NN * 4;
  float*  out   = (float*)d_out;

  const int NGRID = NN / 16;           // 3125
  const int EGRID = NE / 64;           // 25000
  const int PQGRID = (NN + 31) / 32;   // 1563

  // weight split (tiny)
  wt_split<<<(3 * 128 * 256 + 255) / 256, 256, 0, stream>>>(e_w1, W1h, W1l, 256, 3, 257 * 128);
  wt_split<<<(3 * 128 * 128 + 255) / 256, 256, 0, stream>>>(e_w2, W2h, W2l, 128, 3, 128 * 128);
  wt_split<<<(128 * 128 + 255) / 256, 256, 0, stream>>>(c_w1 + (size_t)128 * 128, W3h, W3l, 128, 1, 0);

  // dst-sort (counting sort) once per call; shared by all 3 layers
  hipMemsetAsync(cnt, 0, (size_t)NN * 4, stream);
  hist_kernel<<<(NE + 255) / 256, 256, 0, stream>>>(dst, cnt);
  scan_kernel<<<1, 1024, 0, stream>>>(cnt, nextA);
  slot_kernel<<<(NE + 255) / 256, 256, 0, stream>>>(dst, nextA, permA);

  embed_kernel<<<NGRID, 256, 0, stream>>>(node_attr, emb_w1, emb_b1, ln1_g, ln1_b,
                                          emb_w2, emb_b2, ln2_g, ln2_b, h_hi, h_lo);

  // ---- layer 0 (encoder): coord output discarded
  hipMemsetAsync(h_agg, 0, (size_t)NN * CC * 4, stream);
  pq_kernel<<<PQGRID, 256, 0, stream>>>(h_hi, h_lo, W1h, W1l, e_b1, PQ);
  edge_kernel<0><<<EGRID, 256, 0, stream>>>(permA, src, dst, PQ, xyz,
      e_w1 + (size_t)256 * CC, W2h, W2l, e_b2, W3h, W3l, c_b1, c_w2, h_agg, x_agg);
  node_update<<<NGRID, 256, 0, stream>>>(h_hi, h_lo, h_agg, n_w1, n_b1, n_w2, n_b2,
      h_hi, h_lo, 0, dec_ln_g, dec_ln_b, 0, xyz, x_agg, coord);

  // ---- layer 1 (decoder #1): coord MLP active; input coords = xyz
  hipMemsetAsync(h_agg, 0, (size_t)NN * CC * 4, stream);
  hipMemsetAsync(x_agg, 0, (size_t)NN * 3 * 4, stream);
  pq_kernel<<<PQGRID, 256, 0, stream>>>(h_hi, h_lo, W1h + (size_t)128 * 256,
      W1l + (size_t)128 * 256, e_b1 + CC, PQ);
  edge_kernel<1><<<EGRID, 256, 0, stream>>>(permA, src, dst, PQ, xyz,
      e_w1 + (size_t)(257 + 256) * CC,
      W2h + (size_t)128 * 128, W2l + (size_t)128 * 128, e_b2 + CC,
      W3h, W3l, c_b1 + CC, c_w2 + CC, h_agg, x_agg);
  node_update<<<NGRID, 256, 0, stream>>>(h_hi, h_lo, h_agg,
      n_w1 + (size_t)1 * 256 * CC, n_b1 + CC, n_w2 + (size_t)1 * CC * CC, n_b2 + CC,
      h_hi, h_lo, 1, dec_ln_g, dec_ln_b, 1, xyz, x_agg, coord);

  // ---- layer 2 (decoder #2): coord output discarded; input coords = coord
  hipMemsetAsync(h_agg, 0, (size_t)NN * CC * 4, stream);
  pq_kernel<<<PQGRID, 256, 0, stream>>>(h_hi, h_lo, W1h + (size_t)2 * 128 * 256,
      W1l + (size_t)2 * 128 * 256, e_b1 + 2 * CC, PQ);
  edge_kernel<0><<<EGRID, 256, 0, stream>>>(permA, src, dst, PQ, coord,
      e_w1 + (size_t)(2 * 257 + 256) * CC,
      W2h + (size_t)2 * 128 * 128, W2l + (size_t)2 * 128 * 128, e_b2 + 2 * CC,
      W3h, W3l, c_b1, c_w2, h_agg, x_agg);
  node_update<<<NGRID, 256, 0, stream>>>(h_hi, h_lo, h_agg,
      n_w1 + (size_t)2 * 256 * CC, n_b1 + 2 * CC, n_w2 + (size_t)2 * CC * CC, n_b2 + 2 * CC,
      h_hi, h_lo, 1, dec_ln_g, dec_ln_b, 0, xyz, x_agg, coord);

  out_kernel<<<(NN * 3 + 191) / 192, 192, 0, stream>>>(h_hi, h_lo, out_w, out_b, out);
}

// Round 9
// 2431.441 us; speedup vs baseline: 1.7191x; 1.7191x over previous
//
#include <hip/hip_runtime.h>
#include <hip/hip_fp16.h>
#include <math.h>

#define NN 50000
#define NE 1600000
#define CC 128
#define FIN 64

typedef unsigned short bfr;
typedef __attribute__((ext_vector_type(8))) short short8;
typedef __attribute__((ext_vector_type(4))) float f32x4;

__device__ __forceinline__ f32x4 mfma16(short8 a, short8 b, f32x4 c) {
  return __builtin_amdgcn_mfma_f32_16x16x32_bf16(a, b, c, 0, 0, 0);
}

// silu via v_rcp_f32 (1 ULP) instead of IEEE divide (~10 VALU) — R9 change
__device__ __forceinline__ float silu_f(float x) {
  return x * __builtin_amdgcn_rcpf(1.0f + __expf(-x));
}
__device__ __forceinline__ float gelu_f(float x) { return 0.5f * x * (1.0f + erff(x * 0.7071067811865475f)); }

__device__ __forceinline__ bfr f2bf(float x) {
  unsigned u = __float_as_uint(x);
  unsigned r = (u + 0x7FFFu + ((u >> 16) & 1u)) >> 16;
  return (bfr)r;
}
__device__ __forceinline__ float bf2f(bfr h) { return __uint_as_float(((unsigned)h) << 16); }

// pack the high 16 bits of two fp32 into one u32 (a -> low16, b -> high16)
__device__ __forceinline__ unsigned pack_hi16(unsigned ua, unsigned ub) {
  return __builtin_amdgcn_perm(ub, ua, 0x07060302u);
}

__device__ __forceinline__ float hsum32(float v) {
  v += __shfl_xor(v, 16);
  v += __shfl_xor(v, 8);
  v += __shfl_xor(v, 4);
  v += __shfl_xor(v, 2);
  v += __shfl_xor(v, 1);
  return v;
}

// ============================ dst-sort (counting sort via CSR) ==================================
__global__ __launch_bounds__(256)
void hist_kernel(const int* __restrict__ dst, int* __restrict__ cnt)
{
  const int i = blockIdx.x * 256 + threadIdx.x;
  if (i < NE) atomicAdd(&cnt[dst[i]], 1);
}

__global__ __launch_bounds__(1024)
void scan_kernel(const int* __restrict__ cnt, int* __restrict__ next)
{
  __shared__ int part[1024];
  const int tid = threadIdx.x;
  const int per = (NN + 1023) / 1024;   // 49
  const int base = tid * per;
  int s = 0;
  for (int i = 0; i < per; ++i) {
    const int n = base + i;
    if (n < NN) s += cnt[n];
  }
  part[tid] = s;
  __syncthreads();
  if (tid == 0) {
    int acc = 0;
    for (int i = 0; i < 1024; ++i) { const int t = part[i]; part[i] = acc; acc += t; }
  }
  __syncthreads();
  int off = part[tid];
  for (int i = 0; i < per; ++i) {
    const int n = base + i;
    if (n < NN) { next[n] = off; off += cnt[n]; }
  }
}

__global__ __launch_bounds__(256)
void slot_kernel(const int* __restrict__ dst, int* __restrict__ next, int* __restrict__ perm)
{
  const int i = blockIdx.x * 256 + threadIdx.x;
  if (i < NE) perm[atomicAdd(&next[dst[i]], 1)] = i;
}

// ============================ weight split: Wt_hi/lo[l][n][k] = split(W[l][k][n]) ===============
__global__ __launch_bounds__(256)
void wt_split(const float* __restrict__ W, bfr* __restrict__ Wh, bfr* __restrict__ Wl,
              const int K, const int layers, const int strideIn)
{
  const int gid = blockIdx.x * 256 + threadIdx.x;
  if (gid >= layers * 128 * K) return;
  const int l = gid / (128 * K);
  const int rem = gid - l * 128 * K;
  const int n = rem / K;
  const int k = rem - n * K;
  const float w = W[(size_t)l * strideIn + (size_t)k * 128 + n];
  const bfr hi = f2bf(w);
  Wh[gid] = hi;
  Wl[gid] = f2bf(w - bf2f(hi));
}

// ============================ PQ precompute: P|Q = h @ [W1a|W1b] (+eb1 on P), fp16 out ==========
__global__ __launch_bounds__(256)
void pq_kernel(const bfr* __restrict__ h_hi, const bfr* __restrict__ h_lo,
               const bfr* __restrict__ W1h, const bfr* __restrict__ W1l,
               const float* __restrict__ eb1, __half* __restrict__ PQ)
{
  __shared__ __align__(16) bfr ah[2 * 32 * 136];   // A hi|lo, stride 136 (17,408 B)
  const int tid = threadIdx.x;
  const int n0 = blockIdx.x * 32;
  {
    const int row = tid >> 3, q = tid & 7;
    int n = n0 + row; if (n >= NN) n = NN - 1;
    const uint4* sh = (const uint4*)(h_hi + (size_t)n * CC) + q * 2;
    const uint4* sl = (const uint4*)(h_lo + (size_t)n * CC) + q * 2;
    uint4* dh = (uint4*)(ah + row * 136) + q * 2;
    uint4* dl = (uint4*)(ah + 32 * 136 + row * 136) + q * 2;
    dh[0] = sh[0]; dh[1] = sh[1];
    dl[0] = sl[0]; dl[1] = sl[1];
  }
  __syncthreads();

  const int lane = tid & 63;
  const int li = lane & 15, quad = lane >> 4;
  const int wv = tid >> 6;
  const int c0 = wv * 32 + li, c1 = c0 + 16;

  f32x4 acc[2][4];  // [mi][Pc0, Pc1, Qc0, Qc1]
  {
    const float b0 = eb1[c0], b1 = eb1[c1];
    acc[0][0] = acc[1][0] = (f32x4){b0, b0, b0, b0};
    acc[0][1] = acc[1][1] = (f32x4){b1, b1, b1, b1};
    acc[0][2] = acc[1][2] = (f32x4){0, 0, 0, 0};
    acc[0][3] = acc[1][3] = (f32x4){0, 0, 0, 0};
  }
  const bfr* bp[4] = { W1h + (size_t)c0 * 256, W1h + (size_t)c1 * 256,
                       W1h + (size_t)c0 * 256 + 128, W1h + (size_t)c1 * 256 + 128 };
  const bfr* lp[4] = { W1l + (size_t)c0 * 256, W1l + (size_t)c1 * 256,
                       W1l + (size_t)c0 * 256 + 128, W1l + (size_t)c1 * 256 + 128 };
  #pragma unroll
  for (int ks = 0; ks < 4; ++ks) {
    const int ko = ks * 32 + quad * 8;
    short8 Bh[4], Bl[4];
    #pragma unroll
    for (int o = 0; o < 4; ++o) { Bh[o] = *(const short8*)(bp[o] + ko); Bl[o] = *(const short8*)(lp[o] + ko); }
    #pragma unroll
    for (int mi = 0; mi < 2; ++mi) {
      const int ao = (mi * 16 + li) * 136 + ko;
      const short8 Ah = *(const short8*)(ah + ao);
      const short8 Al = *(const short8*)(ah + 32 * 136 + ao);
      #pragma unroll
      for (int o = 0; o < 4; ++o) {
        acc[mi][o] = mfma16(Ah, Bh[o], acc[mi][o]);
        acc[mi][o] = mfma16(Al, Bh[o], acc[mi][o]);
        acc[mi][o] = mfma16(Ah, Bl[o], acc[mi][o]);
      }
    }
  }
  const int cmap[4] = { c0, c1, 128 + c0, 128 + c1 };
  #pragma unroll
  for (int mi = 0; mi < 2; ++mi) {
    #pragma unroll
    for (int r = 0; r < 4; ++r) {
      const int n = n0 + mi * 16 + quad * 4 + r;
      if (n < NN) {
        __half* po = PQ + (size_t)n * 256;
        #pragma unroll
        for (int o = 0; o < 4; ++o) po[cmap[o]] = __float2half(acc[mi][o][r]);
      }
    }
  }
}

// ============================ edge kernel (dst-sorted; LDS segmented-scan aggregation) ==========
// R7-validated structure (wave owns 2 col-tiles, A via LDS) + rcp-silu (R9).
template<int COORD>
__global__ __launch_bounds__(256)
void edge_kernel(const int* __restrict__ perm,
                 const int* __restrict__ src, const int* __restrict__ dst,
                 const __half* __restrict__ PQ, const float* __restrict__ xyz,
                 const float* __restrict__ w1rad,
                 const bfr* __restrict__ W2h, const bfr* __restrict__ W2l,
                 const float* __restrict__ eb2,
                 const bfr* __restrict__ W3h, const bfr* __restrict__ W3l,
                 const float* __restrict__ cb1, const float* __restrict__ cw2,
                 float* __restrict__ h_agg, float* __restrict__ x_agg)
{
  const int EPB = 64, MOFF = EPB * 136;
  __shared__ __align__(16) bfr mb[2 * EPB * 136];  // 34,816 B; fp32 tbuf alias = 33,792 B
  __shared__ int sidx[EPB], didx[EPB];
  __shared__ float radial[EPB];
  __shared__ float xdn[COORD ? EPB : 1][3];
  __shared__ float sx[COORD ? EPB : 1];
  __shared__ float cw2s[COORD ? 128 : 1];

  const int tid = threadIdx.x;
  const size_t ebase = (size_t)blockIdx.x * EPB;

  if (tid < EPB) {
    const int e = perm[ebase + tid];
    const int s = src[e], d = dst[e];
    sidx[tid] = s; didx[tid] = d;
    const float* xs = xyz + (size_t)s * 3;
    const float* xd = xyz + (size_t)d * 3;
    const float dx = xs[0] - xd[0], dy = xs[1] - xd[1], dz = xs[2] - xd[2];
    const float r = dx * dx + dy * dy + dz * dz;
    radial[tid] = r;
    if (COORD) {
      const float inv = __builtin_amdgcn_rcpf(sqrtf(r) + 1e-30f);
      xdn[tid][0] = dx * inv; xdn[tid][1] = dy * inv; xdn[tid][2] = dz * inv;
    }
  }
  if (COORD && tid >= 128) cw2s[tid - 128] = cw2[tid - 128];
  __syncthreads();

  // m1 = silu(P[src] + Q[dst] + r*w1rad): 4 threads/edge, 32 ch each; trunc hi/lo, packed b128
  {
    const int e = tid >> 2, q = tid & 3, c = q * 32;
    const float r = radial[e];
    const __half* prow = PQ + (size_t)sidx[e] * 256 + c;
    const __half* qrow = PQ + (size_t)didx[e] * 256 + 128 + c;
    #pragma unroll
    for (int i = 0; i < 4; ++i) {
      union { uint4 u; __half2 h2[4]; } pu, qu;
      pu.u = *(const uint4*)(prow + i * 8);
      qu.u = *(const uint4*)(qrow + i * 8);
      const float4 wa = *(const float4*)(w1rad + c + i * 8);
      const float4 wb = *(const float4*)(w1rad + c + i * 8 + 4);
      const float wf[8] = { wa.x, wa.y, wa.z, wa.w, wb.x, wb.y, wb.z, wb.w };
      float v[8];
      #pragma unroll
      for (int j = 0; j < 4; ++j) {
        const float2 p = __half22float2(pu.h2[j]);
        const float2 qq = __half22float2(qu.h2[j]);
        v[2 * j]     = silu_f(p.x + qq.x + r * wf[2 * j]);
        v[2 * j + 1] = silu_f(p.y + qq.y + r * wf[2 * j + 1]);
      }
      uint4 H, L;
      unsigned hw[4], lw[4];
      #pragma unroll
      for (int j = 0; j < 4; ++j) {
        const unsigned ua = __float_as_uint(v[2 * j]);
        const unsigned ub = __float_as_uint(v[2 * j + 1]);
        const float la = v[2 * j]     - __uint_as_float(ua & 0xFFFF0000u);
        const float lb = v[2 * j + 1] - __uint_as_float(ub & 0xFFFF0000u);
        hw[j] = pack_hi16(ua, ub);
        lw[j] = pack_hi16(__float_as_uint(la), __float_as_uint(lb));
      }
      H.x = hw[0]; H.y = hw[1]; H.z = hw[2]; H.w = hw[3];
      L.x = lw[0]; L.y = lw[1]; L.z = lw[2]; L.w = lw[3];
      *(uint4*)(mb + e * 136 + c + i * 8) = H;
      *(uint4*)(mb + MOFF + e * 136 + c + i * 8) = L;
    }
  }
  __syncthreads();

  const int lane = tid & 63;
  const int li = lane & 15, quad = lane >> 4;
  const int wv = tid >> 6;
  const int c0 = wv * 32 + li, c1 = c0 + 16;

  // ---- GEMM2: m1[64x128]@[128x128], bf16x3 -> silu (in regs) ---------------------------------
  f32x4 mm[4][2];
  {
    const float b0 = eb2[c0], b1 = eb2[c1];
    #pragma unroll
    for (int mi = 0; mi < 4; ++mi) {
      mm[mi][0] = (f32x4){b0, b0, b0, b0};
      mm[mi][1] = (f32x4){b1, b1, b1, b1};
    }
  }
  {
    const bfr* bh0 = W2h + (size_t)c0 * 128 + quad * 8;
    const bfr* bh1 = W2h + (size_t)c1 * 128 + quad * 8;
    const bfr* bl0 = W2l + (size_t)c0 * 128 + quad * 8;
    const bfr* bl1 = W2l + (size_t)c1 * 128 + quad * 8;
    #pragma unroll
    for (int ks = 0; ks < 4; ++ks) {
      const short8 Bh0 = *(const short8*)(bh0 + ks * 32);
      const short8 Bh1 = *(const short8*)(bh1 + ks * 32);
      const short8 Bl0 = *(const short8*)(bl0 + ks * 32);
      const short8 Bl1 = *(const short8*)(bl1 + ks * 32);
      #pragma unroll
      for (int mi = 0; mi < 4; ++mi) {
        const int ao = (mi * 16 + li) * 136 + ks * 32 + quad * 8;
        const short8 Ah = *(const short8*)(mb + ao);
        const short8 Al = *(const short8*)(mb + MOFF + ao);
        mm[mi][0] = mfma16(Ah, Bh0, mm[mi][0]);
        mm[mi][0] = mfma16(Al, Bh0, mm[mi][0]);
        mm[mi][0] = mfma16(Ah, Bl0, mm[mi][0]);
        mm[mi][1] = mfma16(Ah, Bh1, mm[mi][1]);
        mm[mi][1] = mfma16(Al, Bh1, mm[mi][1]);
        mm[mi][1] = mfma16(Ah, Bl1, mm[mi][1]);
      }
    }
  }
  #pragma unroll
  for (int mi = 0; mi < 4; ++mi) {
    #pragma unroll
    for (int r = 0; r < 4; ++r) {
      mm[mi][0][r] = silu_f(mm[mi][0][r]);
      mm[mi][1][r] = silu_f(mm[mi][1][r]);
    }
  }
  __syncthreads();   // all GEMM2 A-reads of mb complete

  if (!COORD) {
    // ---- m fp32 into tbuf (mb alias, stride 132) -> per-channel segmented scan ----------------
    float* tbuf = (float*)mb;
    #pragma unroll
    for (int mi = 0; mi < 4; ++mi) {
      #pragma unroll
      for (int r = 0; r < 4; ++r) {
        const int row = mi * 16 + quad * 4 + r;
        tbuf[row * 132 + c0] = mm[mi][0][r];
        tbuf[row * 132 + c1] = mm[mi][1][r];
      }
    }
    __syncthreads();
    const int c = tid & 127, half = tid >> 7;
    const int j0 = half * 32, j1 = j0 + 32;
    float s = 0.0f;
    for (int j = j0; j < j1; ++j) {
      s += tbuf[j * 132 + c];
      const int dj = didx[j];
      if (j == j1 - 1 || didx[j + 1] != dj) {
        atomicAdd(&h_agg[(size_t)dj * CC + c], s);
        s = 0.0f;
      }
    }
  } else {
    // ---- m hi/lo (trunc) back into mb (A of GEMM3) -------------------------------------------
    #pragma unroll
    for (int mi = 0; mi < 4; ++mi) {
      #pragma unroll
      for (int r = 0; r < 4; ++r) {
        const int row = mi * 16 + quad * 4 + r;
        const float v0 = mm[mi][0][r], v1 = mm[mi][1][r];
        const unsigned u0 = __float_as_uint(v0), u1 = __float_as_uint(v1);
        mb[row * 136 + c0] = (bfr)(u0 >> 16);
        mb[row * 136 + c1] = (bfr)(u1 >> 16);
        const float l0 = v0 - __uint_as_float(u0 & 0xFFFF0000u);
        const float l1 = v1 - __uint_as_float(u1 & 0xFFFF0000u);
        mb[MOFF + row * 136 + c0] = (bfr)(__float_as_uint(l0) >> 16);
        mb[MOFF + row * 136 + c1] = (bfr)(__float_as_uint(l1) >> 16);
      }
    }
    __syncthreads();
    // ---- segmented scan over hi+lo -----------------------------------------------------------
    {
      const int c = tid & 127, half = tid >> 7;
      const int j0 = half * 32, j1 = j0 + 32;
      float s = 0.0f;
      for (int j = j0; j < j1; ++j) {
        s += bf2f(mb[j * 136 + c]) + bf2f(mb[MOFF + j * 136 + c]);
        const int dj = didx[j];
        if (j == j1 - 1 || didx[j + 1] != dj) {
          atomicAdd(&h_agg[(size_t)dj * CC + c], s);
          s = 0.0f;
        }
      }
    }
    // ---- GEMM3: m[64x128]@cw1, bf16x3 -> silu -> t; cm = t . cw2; segmented x_agg flush ------
    f32x4 tt[4][2];
    {
      const float b0 = cb1[c0], b1 = cb1[c1];
      #pragma unroll
      for (int mi = 0; mi < 4; ++mi) {
        tt[mi][0] = (f32x4){b0, b0, b0, b0};
        tt[mi][1] = (f32x4){b1, b1, b1, b1};
      }
    }
    {
      const bfr* bh0 = W3h + (size_t)c0 * 128 + quad * 8;
      const bfr* bh1 = W3h + (size_t)c1 * 128 + quad * 8;
      const bfr* bl0 = W3l + (size_t)c0 * 128 + quad * 8;
      const bfr* bl1 = W3l + (size_t)c1 * 128 + quad * 8;
      #pragma unroll
      for (int ks = 0; ks < 4; ++ks) {
        const short8 Bh0 = *(const short8*)(bh0 + ks * 32);
        const short8 Bh1 = *(const short8*)(bh1 + ks * 32);
        const short8 Bl0 = *(const short8*)(bl0 + ks * 32);
        const short8 Bl1 = *(const short8*)(bl1 + ks * 32);
        #pragma unroll
        for (int mi = 0; mi < 4; ++mi) {
          const int ao = (mi * 16 + li) * 136 + ks * 32 + quad * 8;
          const short8 Ah = *(const short8*)(mb + ao);
          const short8 Al = *(const short8*)(mb + MOFF + ao);
          tt[mi][0] = mfma16(Ah, Bh0, tt[mi][0]);
          tt[mi][0] = mfma16(Al, Bh0, tt[mi][0]);
          tt[mi][0] = mfma16(Ah, Bl0, tt[mi][0]);
          tt[mi][1] = mfma16(Ah, Bh1, tt[mi][1]);
          tt[mi][1] = mfma16(Al, Bh1, tt[mi][1]);
          tt[mi][1] = mfma16(Ah, Bl1, tt[mi][1]);
        }
      }
    }
    __syncthreads();   // scan + GEMM3 reads of mb done before alias
    float* tbuf = (float*)mb;  // 64 x 132 fp32
    #pragma unroll
    for (int mi = 0; mi < 4; ++mi) {
      #pragma unroll
      for (int r = 0; r < 4; ++r) {
        const int row = mi * 16 + quad * 4 + r;
        tbuf[row * 132 + c0] = silu_f(tt[mi][0][r]);
        tbuf[row * 132 + c1] = silu_f(tt[mi][1][r]);
      }
    }
    __syncthreads();
    if (tid < EPB) {
      float s = 0.0f;
      #pragma unroll 8
      for (int k = 0; k < CC; ++k) s += tbuf[tid * 132 + k] * cw2s[k];
      sx[tid] = s;
    }
    __syncthreads();
    if (tid < 6) {
      const int c = tid >> 1, half = tid & 1;
      const int j0 = half * 32, j1 = j0 + 32;
      float a = 0.0f;
      for (int j = j0; j < j1; ++j) {
        a += sx[j] * xdn[j][c];
        const int dj = didx[j];
        if (j == j1 - 1 || didx[j + 1] != dj) {
          atomicAdd(&x_agg[(size_t)dj * 3 + c], a);
          a = 0.0f;
        }
      }
    }
  }
}

// ============================ fp32 node-side kernels (validated R3/R5) ==========================
template<int K, int ROWS>
__device__ __forceinline__ void mm_tile(const float* __restrict__ fb, const int fstride,
                                        const float* __restrict__ W, const float* __restrict__ bias,
                                        const int c0, const int r0, float (&acc)[ROWS][4])
{
  const float4 b = *(const float4*)(bias + c0);
  #pragma unroll
  for (int i = 0; i < ROWS; ++i) { acc[i][0] = b.x; acc[i][1] = b.y; acc[i][2] = b.z; acc[i][3] = b.w; }
  #pragma unroll 2
  for (int k = 0; k < K; k += 4) {
    const float4 w0 = *(const float4*)(W + (size_t)(k + 0) * CC + c0);
    const float4 w1 = *(const float4*)(W + (size_t)(k + 1) * CC + c0);
    const float4 w2 = *(const float4*)(W + (size_t)(k + 2) * CC + c0);
    const float4 w3 = *(const float4*)(W + (size_t)(k + 3) * CC + c0);
    #pragma unroll
    for (int i = 0; i < ROWS; ++i) {
      const float4 f = *(const float4*)(fb + (r0 + i) * fstride + k);
      acc[i][0] += f.x * w0.x + f.y * w1.x + f.z * w2.x + f.w * w3.x;
      acc[i][1] += f.x * w0.y + f.y * w1.y + f.z * w2.y + f.w * w3.y;
      acc[i][2] += f.x * w0.z + f.y * w1.z + f.z * w2.z + f.w * w3.z;
      acc[i][3] += f.x * w0.w + f.y * w1.w + f.z * w2.w + f.w * w3.w;
    }
  }
}

__device__ __forceinline__ void ln_then_gelu(float (&v)[4], const float* __restrict__ g,
                                             const float* __restrict__ b, const int c0)
{
  const float mu = hsum32(v[0] + v[1] + v[2] + v[3]) * (1.0f / 128.0f);
  const float d0 = v[0] - mu, d1 = v[1] - mu, d2 = v[2] - mu, d3 = v[3] - mu;
  const float var = hsum32(d0 * d0 + d1 * d1 + d2 * d2 + d3 * d3) * (1.0f / 128.0f);
  const float rs = rsqrtf(var + 1e-5f);
  const float4 gv = *(const float4*)(g + c0);
  const float4 bv = *(const float4*)(b + c0);
  v[0] = gelu_f(d0 * rs * gv.x + bv.x);
  v[1] = gelu_f(d1 * rs * gv.y + bv.y);
  v[2] = gelu_f(d2 * rs * gv.z + bv.z);
  v[3] = gelu_f(d3 * rs * gv.w + bv.w);
}

__device__ __forceinline__ void store_hilo4(bfr* __restrict__ hi, bfr* __restrict__ lo,
                                            const float v0, const float v1,
                                            const float v2, const float v3)
{
  ushort4 h, l;
  h.x = f2bf(v0); h.y = f2bf(v1); h.z = f2bf(v2); h.w = f2bf(v3);
  l.x = f2bf(v0 - bf2f(h.x)); l.y = f2bf(v1 - bf2f(h.y));
  l.z = f2bf(v2 - bf2f(h.z)); l.w = f2bf(v3 - bf2f(h.w));
  *(ushort4*)hi = h;
  *(ushort4*)lo = l;
}

__global__ __launch_bounds__(256)
void node_update(const bfr* __restrict__ h_hi, const bfr* __restrict__ h_lo,
                 const float* __restrict__ h_agg,
                 const float* __restrict__ nw1, const float* __restrict__ nb1,
                 const float* __restrict__ nw2, const float* __restrict__ nb2,
                 bfr* __restrict__ ho_hi, bfr* __restrict__ ho_lo, const int post_ln,
                 const float* __restrict__ lng, const float* __restrict__ lnb,
                 const int do_coord, const float* __restrict__ xin,
                 const float* __restrict__ x_agg, float* __restrict__ coord_out)
{
  const int FS2 = 260, MS = 132;
  __shared__ float fin[16 * FS2];
  __shared__ float hid[16 * MS];
  const int tid = threadIdx.x;
  const size_t n0 = (size_t)blockIdx.x * 16;
  {
    const int n = tid >> 4, q = tid & 15;
    const uint4 vh = *(const uint4*)(h_hi + (n0 + n) * CC + q * 8);
    const uint4 vl = *(const uint4*)(h_lo + (n0 + n) * CC + q * 8);
    const unsigned short* hp = (const unsigned short*)&vh;
    const unsigned short* lp = (const unsigned short*)&vl;
    float* fo = fin + n * FS2 + q * 8;
    #pragma unroll
    for (int i = 0; i < 8; ++i) fo[i] = bf2f(hp[i]) + bf2f(lp[i]);
    const float4* s2 = (const float4*)(h_agg + (n0 + n) * CC + q * 8);
    float4* d2 = (float4*)(fin + n * FS2 + CC + q * 8);
    d2[0] = s2[0]; d2[1] = s2[1];
  }
  if (do_coord && tid < 48) {
    const int n = tid / 3, d = tid % 3;
    coord_out[(n0 + n) * 3 + d] = xin[(n0 + n) * 3 + d] + x_agg[(n0 + n) * 3 + d];
  }
  __syncthreads();
  const int cg = tid & 31, ng = tid >> 5;
  const int c0 = cg * 4, m0 = ng * 2;
  float acc[2][4];
  mm_tile<256, 2>(fin, FS2, nw1, nb1, c0, m0, acc);
  #pragma unroll
  for (int i = 0; i < 2; ++i) {
    float4 o;
    o.x = silu_f(acc[i][0]); o.y = silu_f(acc[i][1]); o.z = silu_f(acc[i][2]); o.w = silu_f(acc[i][3]);
    *(float4*)(hid + (m0 + i) * MS + c0) = o;
  }
  __syncthreads();
  float acc2[2][4];
  mm_tile<128, 2>(hid, MS, nw2, nb2, c0, m0, acc2);
  if (post_ln) {
    #pragma unroll
    for (int i = 0; i < 2; ++i) {
      float v[4] = { gelu_f(acc2[i][0]), gelu_f(acc2[i][1]), gelu_f(acc2[i][2]), gelu_f(acc2[i][3]) };
      const float mu = hsum32(v[0] + v[1] + v[2] + v[3]) * (1.0f / 128.0f);
      const float d0 = v[0] - mu, d1 = v[1] - mu, d2 = v[2] - mu, d3 = v[3] - mu;
      const float var = hsum32(d0 * d0 + d1 * d1 + d2 * d2 + d3 * d3) * (1.0f / 128.0f);
      const float rs = rsqrtf(var + 1e-5f);
      const float4 gv = *(const float4*)(lng + c0);
      const float4 bv = *(const float4*)(lnb + c0);
      acc2[i][0] = d0 * rs * gv.x + bv.x; acc2[i][1] = d1 * rs * gv.y + bv.y;
      acc2[i][2] = d0 * 0.0f + d2 * rs * gv.z + bv.z; acc2[i][3] = d3 * rs * gv.w + bv.w;
    }
  }
  #pragma unroll
  for (int i = 0; i < 2; ++i)
    store_hilo4(ho_hi + (n0 + m0 + i) * CC + c0, ho_lo + (n0 + m0 + i) * CC + c0,
                acc2[i][0], acc2[i][1], acc2[i][2], acc2[i][3]);
}

__global__ __launch_bounds__(256)
void embed_kernel(const float* __restrict__ na,
                  const float* __restrict__ w1, const float* __restrict__ b1,
                  const float* __restrict__ g1, const float* __restrict__ be1,
                  const float* __restrict__ w2, const float* __restrict__ b2,
                  const float* __restrict__ g2, const float* __restrict__ be2,
                  bfr* __restrict__ ho_hi, bfr* __restrict__ ho_lo)
{
  const int AS = 68, MS = 132;
  __shared__ float ain[16 * AS];
  __shared__ float hb[16 * MS];
  const int tid = threadIdx.x;
  const size_t n0 = (size_t)blockIdx.x * 16;
  {
    const int n = tid >> 4, q = tid & 15;
    *(float4*)(ain + n * AS + q * 4) = *(const float4*)(na + (n0 + n) * FIN + q * 4);
  }
  __syncthreads();
  const int cg = tid & 31, ng = tid >> 5;
  const int c0 = cg * 4, m0 = ng * 2;
  float acc[2][4];
  mm_tile<64, 2>(ain, AS, w1, b1, c0, m0, acc);
  #pragma unroll
  for (int i = 0; i < 2; ++i) {
    ln_then_gelu(acc[i], g1, be1, c0);
    *(float4*)(hb + (m0 + i) * MS + c0) = make_float4(acc[i][0], acc[i][1], acc[i][2], acc[i][3]);
  }
  __syncthreads();
  float acc2[2][4];
  mm_tile<128, 2>(hb, MS, w2, b2, c0, m0, acc2);
  #pragma unroll
  for (int i = 0; i < 2; ++i) {
    ln_then_gelu(acc2[i], g2, be2, c0);
    store_hilo4(ho_hi + (n0 + m0 + i) * CC + c0, ho_lo + (n0 + m0 + i) * CC + c0,
                acc2[i][0], acc2[i][1], acc2[i][2], acc2[i][3]);
  }
}

__global__ __launch_bounds__(192)
void out_kernel(const bfr* __restrict__ h_hi, const bfr* __restrict__ h_lo,
                const float* __restrict__ w, const float* __restrict__ b,
                float* __restrict__ out)
{
  const int gid = blockIdx.x * 192 + threadIdx.x;
  if (gid >= NN * 3) return;
  const int n = gid / 3, j = gid % 3;
  float acc = b[j];
  const bfr* hh = h_hi + (size_t)n * CC;
  const bfr* hl = h_lo + (size_t)n * CC;
  #pragma unroll 4
  for (int k = 0; k < CC; ++k) acc += (bf2f(hh[k]) + bf2f(hl[k])) * w[k * 3 + j];
  out[gid] = acc;
}

// ================================================================================================
extern "C" void kernel_launch(void* const* d_in, const int* in_sizes, int n_in,
                              void* d_out, int out_size, void* d_ws, size_t ws_size,
                              hipStream_t stream)
{
  (void)in_sizes; (void)n_in; (void)out_size; (void)ws_size;
  const int*   src       = (const int*)d_in[0];
  const int*   dst       = (const int*)d_in[1];
  const float* node_attr = (const float*)d_in[2];
  const float* xyz       = (const float*)d_in[3];
  const float* emb_w1    = (const float*)d_in[4];
  const float* emb_b1    = (const float*)d_in[5];
  const float* ln1_g     = (const float*)d_in[6];
  const float* ln1_b     = (const float*)d_in[7];
  const float* emb_w2    = (const float*)d_in[8];
  const float* emb_b2    = (const float*)d_in[9];
  const float* ln2_g     = (const float*)d_in[10];
  const float* ln2_b     = (const float*)d_in[11];
  const float* e_w1      = (const float*)d_in[12];
  const float* e_b1      = (const float*)d_in[13];
  const float* e_w2      = (const float*)d_in[14];
  const float* e_b2      = (const float*)d_in[15];
  const float* n_w1      = (const float*)d_in[16];
  const float* n_b1      = (const float*)d_in[17];
  const float* n_w2      = (const float*)d_in[18];
  const float* n_b2      = (const float*)d_in[19];
  const float* c_w1      = (const float*)d_in[20];
  const float* c_b1      = (const float*)d_in[21];
  const float* c_w2      = (const float*)d_in[22];
  const float* dec_ln_g  = (const float*)d_in[23];
  const float* dec_ln_b  = (const float*)d_in[24];
  const float* out_w     = (const float*)d_in[25];
  const float* out_b     = (const float*)d_in[26];

  // workspace layout (~86 MB total)
  char* wsb = (char*)d_ws;
  float*  h_agg = (float*)wsb;                      wsb += (size_t)NN * CC * 4;   // 25.6 MB
  __half* PQ    = (__half*)wsb;                     wsb += (size_t)NN * 256 * 2;  // 25.6 MB
  float*  x_agg = (float*)wsb;                      wsb += (size_t)NN * 3 * 4;
  float*  coord = (float*)wsb;                      wsb += (size_t)NN * 3 * 4;
  bfr*    h_hi  = (bfr*)wsb;                        wsb += (size_t)NN * CC * 2;   // 12.8 MB
  bfr*    h_lo  = (bfr*)wsb;                        wsb += (size_t)NN * CC * 2;   // 12.8 MB
  bfr*    W1h   = (bfr*)wsb;                        wsb += (size_t)3 * 128 * 256 * 2;
  bfr*    W1l   = (bfr*)wsb;                        wsb += (size_t)3 * 128 * 256 * 2;
  bfr*    W2h   = (bfr*)wsb;                        wsb += (size_t)3 * 128 * 128 * 2;
  bfr*    W2l   = (bfr*)wsb;                        wsb += (size_t)3 * 128 * 128 * 2;
  bfr*    W3h   = (bfr*)wsb;                        wsb += (size_t)128 * 128 * 2;
  bfr*    W3l   = (bfr*)wsb;                        wsb += (size_t)128 * 128 * 2;
  int*    permA = (int*)wsb;                        wsb += (size_t)NE * 4;        // 6.4 MB
  int*    cnt   = (int*)wsb;                        wsb += (size_t)NN * 4;
  int*    nextA = (int*)wsb;                        wsb += (size_t)NN * 4;
  float*  out   = (float*)d_out;

  const int NGRID = NN / 16;           // 3125
  const int EGRID = NE / 64;           // 25000
  const int PQGRID = (NN + 31) / 32;   // 1563

  // weight split (tiny)
  wt_split<<<(3 * 128 * 256 + 255) / 256, 256, 0, stream>>>(e_w1, W1h, W1l, 256, 3, 257 * 128);
  wt_split<<<(3 * 128 * 128 + 255) / 256, 256, 0, stream>>>(e_w2, W2h, W2l, 128, 3, 128 * 128);
  wt_split<<<(128 * 128 + 255) / 256, 256, 0, stream>>>(c_w1 + (size_t)128 * 128, W3h, W3l, 128, 1, 0);

  // dst-sort (counting sort) once per call; shared by all 3 layers
  hipMemsetAsync(cnt, 0, (size_t)NN * 4, stream);
  hist_kernel<<<(NE + 255) / 256, 256, 0, stream>>>(dst, cnt);
  scan_kernel<<<1, 1024, 0, stream>>>(cnt, nextA);
  slot_kernel<<<(NE + 255) / 256, 256, 0, stream>>>(dst, nextA, permA);

  embed_kernel<<<NGRID, 256, 0, stream>>>(node_attr, emb_w1, emb_b1, ln1_g, ln1_b,
                                          emb_w2, emb_b2, ln2_g, ln2_b, h_hi, h_lo);

  // ---- layer 0 (encoder): coord output discarded
  hipMemsetAsync(h_agg, 0, (size_t)NN * CC * 4, stream);
  pq_kernel<<<PQGRID, 256, 0, stream>>>(h_hi, h_lo, W1h, W1l, e_b1, PQ);
  edge_kernel<0><<<EGRID, 256, 0, stream>>>(permA, src, dst, PQ, xyz,
      e_w1 + (size_t)256 * CC, W2h, W2l, e_b2, W3h, W3l, c_b1, c_w2, h_agg, x_agg);
  node_update<<<NGRID, 256, 0, stream>>>(h_hi, h_lo, h_agg, n_w1, n_b1, n_w2, n_b2,
      h_hi, h_lo, 0, dec_ln_g, dec_ln_b, 0, xyz, x_agg, coord);

  // ---- layer 1 (decoder #1): coord MLP active; input coords = xyz
  hipMemsetAsync(h_agg, 0, (size_t)NN * CC * 4, stream);
  hipMemsetAsync(x_agg, 0, (size_t)NN * 3 * 4, stream);
  pq_kernel<<<PQGRID, 256, 0, stream>>>(h_hi, h_lo, W1h + (size_t)128 * 256,
      W1l + (size_t)128 * 256, e_b1 + CC, PQ);
  edge_kernel<1><<<EGRID, 256, 0, stream>>>(permA, src, dst, PQ, xyz,
      e_w1 + (size_t)(257 + 256) * CC,
      W2h + (size_t)128 * 128, W2l + (size_t)128 * 128, e_b2 + CC,
      W3h, W3l, c_b1 + CC, c_w2 + CC, h_agg, x_agg);
  node_update<<<NGRID, 256, 0, stream>>>(h_hi, h_lo, h_agg,
      n_w1 + (size_t)1 * 256 * CC, n_b1 + CC, n_w2 + (size_t)1 * CC * CC, n_b2 + CC,
      h_hi, h_lo, 1, dec_ln_g, dec_ln_b, 1, xyz, x_agg, coord);

  // ---- layer 2 (decoder #2): coord output discarded; input coords = coord
  hipMemsetAsync(h_agg, 0, (size_t)NN * CC * 4, stream);
  pq_kernel<<<PQGRID, 256, 0, stream>>>(h_hi, h_lo, W1h + (size_t)2 * 128 * 256,
      W1l + (size_t)2 * 128 * 256, e_b1 + 2 * CC, PQ);
  edge_kernel<0><<<EGRID, 256, 0, stream>>>(permA, src, dst, PQ, coord,
      e_w1 + (size_t)(2 * 257 + 256) * CC,
      W2h + (size_t)2 * 128 * 128, W2l + (size_t)2 * 128 * 128, e_b2 + 2 * CC,
      W3h, W3l, c_b1, c_w2, h_agg, x_agg);
  node_update<<<NGRID, 256, 0, stream>>>(h_hi, h_lo, h_agg,
      n_w1 + (size_t)2 * 256 * CC, n_b1 + 2 * CC, n_w2 + (size_t)2 * CC * CC, n_b2 + 2 * CC,
      h_hi, h_lo, 1, dec_ln_g, dec_ln_b, 0, xyz, x_agg, coord);

  out_kernel<<<(NN * 3 + 191) / 192, 192, 0, stream>>>(h_hi, h_lo, out_w, out_b, out);
}